// Round 10
// baseline (421.278 us; speedup 1.0000x reference)
//
#include <hip/hip_runtime.h>

typedef _Float16 f16;
typedef f16 f16x2 __attribute__((ext_vector_type(2)));
typedef f16 f16x8 __attribute__((ext_vector_type(8)));
typedef float f32x4 __attribute__((ext_vector_type(4)));
typedef float f32x16 __attribute__((ext_vector_type(16)));
typedef unsigned int uint;

#define NCH 16
#define NB 32
#define NH 256
#define NW 256
#define HW 65536
#define CHW 1048576

// ws global image from prep_k: f16x8 frag idx WF1=0, WF2=1024, WF3=3072, WF4=5120
// bias f32 frags at byte 90112
#define BIAS_BYTE_G 90112

// LDS layout (bytes): L2 A-frags 0..32768, L3 A-frags 32768..65536,
// bias 65536..67072, x-tile 67072..77952
#define L2A_OFF 0
#define L3A_OFF 32768
#define BIAS_OFF 65536
#define XT_OFF 67072
#define LDS_TOTAL 77952

__global__ void prep_k(const float* __restrict__ w1, const float* __restrict__ w2,
                       const float* __restrict__ w3, const float* __restrict__ w4,
                       const float* __restrict__ b1, const float* __restrict__ b2,
                       const float* __restrict__ b3, float* __restrict__ wsf) {
  f16* wf = (f16*)wsf;
  int id = blockIdx.x * 256 + threadIdx.x;
  if (id < 8192) {
    int j = id & 7, l = (id >> 3) & 63, mt = (id >> 9) & 3, kt = id >> 11;
    int o = mt * 32 + (l & 31), c = kt * 16 + (l >> 5) * 8 + j;
    wf[id] = (f16)w1[o * 64 + c];
  } else if (id < 24576) {
    int t = id - 8192;
    int j = t & 7, l = (t >> 3) & 63, mt = (t >> 9) & 3, kt = t >> 11;
    int o = mt * 32 + (l & 31), c = kt * 16 + (l >> 5) * 8 + j;
    wf[8192 + t] = (f16)w2[o * 128 + c];
  } else if (id < 40960) {
    int t = id - 24576;
    int j = t & 7, l = (t >> 3) & 63, mt = (t >> 9) & 3, kt = t >> 11;
    int o = mt * 32 + (l & 31), c = kt * 16 + (l >> 5) * 8 + j;
    wf[24576 + t] = (f16)w3[o * 128 + c];
  } else if (id < 45056) {
    int t = id - 40960;
    int j = t & 7, l = (t >> 3) & 63, kt = t >> 9;
    int m = l & 31, hh = l >> 5;
    int c = kt * 16 + hh * 8 + j;
    wf[40960 + t] = (m < 16) ? (f16)w4[m * 128 + c] : (f16)0.f;
  } else if (id < 45440) {
    int t = id - 45056;
    int r = t & 15, hh = (t >> 4) & 1, mt = (t >> 5) & 3, ly = t >> 7;
    const float* bb = (ly == 0) ? b1 : (ly == 1) ? b2 : b3;
    ((float*)((unsigned char*)wsf + BIAS_BYTE_G))[t] =
        bb[mt * 32 + (r & 3) + 8 * (r >> 2) + 4 * hh];
  }
}

__device__ __forceinline__ void pl32swap(uint& a, uint& b) {
  asm volatile("v_permlane32_swap_b32 %0, %1" : "+v"(a), "+v"(b));
}

__device__ __forceinline__ f16x8 mk8(uint a, uint b, uint c, uint d) {
  union { uint u[4]; f16x8 v; } z;
  z.u[0] = a; z.u[1] = b; z.u[2] = c; z.u[3] = d;
  return z.v;
}

__device__ __forceinline__ void gload_lds16(const void* g, void* l) {
  __builtin_amdgcn_global_load_lds(
      (const __attribute__((address_space(1))) unsigned int*)g,
      (__attribute__((address_space(3))) unsigned int*)l, 16, 0, 0);
}

__device__ __forceinline__ void epilogue_swap(const f32x16 acc[4], f16x8 Bn[8]) {
  uint w[32];
#pragma unroll
  for (int mt = 0; mt < 4; ++mt) {
#pragma unroll
    for (int i = 0; i < 8; ++i) {
      float v0 = acc[mt][2 * i], v1 = acc[mt][2 * i + 1];
      v0 = fmaxf(v0, 0.01f * v0);
      v1 = fmaxf(v1, 0.01f * v1);
      f16x2 t; t[0] = (f16)v0; t[1] = (f16)v1;
      w[mt * 8 + i] = __builtin_bit_cast(uint, t);
    }
  }
#pragma unroll
  for (int kt = 0; kt < 8; ++kt) {
    int mt = kt >> 1, sub = kt & 1;
    int W = mt * 8 + sub * 4;
    uint a0 = w[W], a1 = w[W + 1], a2 = w[W + 2], a3 = w[W + 3];
    pl32swap(a0, a2);
    pl32swap(a1, a3);
    Bn[kt] = mk8(a0, a1, a2, a3);
  }
}

// acc[mt] = bias frags from LDS
__device__ __forceinline__ void bias_init(const unsigned char* smem, int lyF32Off,
                                          int hi, f32x16 acc[4]) {
  const float* bf = (const float*)(smem + BIAS_OFF) + lyF32Off;
#pragma unroll
  for (int mt = 0; mt < 4; ++mt) {
#pragma unroll
    for (int q = 0; q < 4; ++q) {
      f32x4 bv = *(const f32x4*)(bf + (mt * 2 + hi) * 16 + q * 4);
#pragma unroll
      for (int e = 0; e < 4; ++e) acc[mt][q * 4 + e] = bv[e];
    }
  }
}

// single-half layer with A-frags from LDS
template <int NKT>
__device__ __forceinline__ void gemm_lds(const unsigned char* smem, int aOff, int lane,
                                         const f16x8* __restrict__ B, f32x16 acc[4]) {
  const f16x8* A = (const f16x8*)(smem + aOff) + lane;
#pragma unroll
  for (int kt = 0; kt < NKT; ++kt) {
#pragma unroll
    for (int mt = 0; mt < 4; ++mt) {
      f16x8 a = A[(kt * 4 + mt) * 64];
      acc[mt] = __builtin_amdgcn_mfma_f32_32x32x16_f16(a, B[kt], acc[mt], 0, 0, 0);
    }
  }
}

// perception for 32-px wave from packed f16 tile: 9 b128 reads -> L1 B-frags
__device__ __forceinline__ void perception(const unsigned char* __restrict__ xtb,
                                           int wv, int pc, int hi, f16x8 B1h[4]) {
  union U4 { uint4 u; f16 hh[8]; };
  const unsigned char* xp = xtb + (size_t)(wv * 34 + pc) * 32 + hi * 16;
  U4 q[9];
#pragma unroll
  for (int dr = 0; dr < 3; ++dr)
#pragma unroll
    for (int dc = 0; dc < 3; ++dc)
      q[dr * 3 + dc].u = *(const uint4*)(xp + (dr * 34 + dc) * 32);
  uint yw[16];
#pragma unroll
  for (int j = 0; j < 8; ++j) {
    float s0 = (float)q[0].hh[j], s1 = (float)q[1].hh[j], s2 = (float)q[2].hh[j];
    float s3 = (float)q[3].hh[j], s5 = (float)q[5].hh[j];
    float s6 = (float)q[6].hh[j], s7 = (float)q[7].hh[j], s8 = (float)q[8].hh[j];
    float c4 = (float)q[4].hh[j];
    float rs0 = s0 + s1 + s2, rs2 = s6 + s7 + s8;
    float fsx = (s2 - s0) + (s8 - s6) + 2.f * (s5 - s3);
    float fsy = (rs2 - rs0) + (s7 - s1);
    float flap = (rs0 + rs2 + s3 + s5) - 8.f * c4;
    f16x2 t0; t0[0] = q[4].hh[j]; t0[1] = (f16)fsx;
    f16x2 t1; t1[0] = (f16)fsy; t1[1] = (f16)flap;
    int kt = j >> 1, cp = j & 1;
    yw[kt * 4 + cp * 2 + 0] = __builtin_bit_cast(uint, t0);
    yw[kt * 4 + cp * 2 + 1] = __builtin_bit_cast(uint, t1);
  }
#pragma unroll
  for (int kt = 0; kt < 4; ++kt)
    B1h[kt] = mk8(yw[kt * 4], yw[kt * 4 + 1], yw[kt * 4 + 2], yw[kt * 4 + 3]);
}

__global__ __launch_bounds__(512, 4)
void nca_mlp_k(const float* __restrict__ x, const float* __restrict__ wsf,
               const float* __restrict__ mask, float* __restrict__ xn) {
  extern __shared__ unsigned char smem[];
  unsigned char* xtb = smem + XT_OFF;
  const int tid = threadIdx.x;
  const int lane = tid & 63;
  const int wv = tid >> 6;     // 0..7 = tile row
  const int pc = lane & 31;
  const int hi = lane >> 5;
  const int c0 = blockIdx.x * 32;
  const int r0 = blockIdx.y * 8;
  const int b = blockIdx.z;
  const float* xb = x + (size_t)b * CHW;

  // ---- preload L1 A-frags from global (L2-broadcast, hidden under staging) ----
  const f16x8* wp = (const f16x8*)wsf;
  f16x8 A1[16];
#pragma unroll
  for (int f = 0; f < 16; ++f) A1[f] = wp[f * 64 + lane];

  // ---- DMA L2/L3 A-frags + bias into LDS (zero VGPR) ----
  {
    const unsigned char* wsB = (const unsigned char*)wsf;
    for (int i = tid; i < 4192; i += 512) {
      if (i < 4096) gload_lds16(wsB + 16384 + i * 16, smem + i * 16);
      else          gload_lds16(wsB + BIAS_BYTE_G + (i - 4096) * 16,
                                smem + BIAS_OFF + (i - 4096) * 16);
    }
  }
  // ---- stage x tile: f16, channel-permuted [rr10][cc34][16] ----
  {
    for (int i = tid; i < 340; i += 512) {
      int rr = i / 34, cc = i - rr * 34;
      int gr = r0 - 1 + rr, gc = c0 - 1 + cc;
      bool ok = ((unsigned)gr < NH) && ((unsigned)gc < NW);
      union { f16 h[16]; uint4 u4[2]; } z;
#pragma unroll
      for (int ch = 0; ch < 16; ++ch) {
        float v = ok ? xb[(ch << 16) + (gr << 8) + gc] : 0.f;
        int s = ((ch >> 1) & 1) * 8 + (ch >> 2) * 2 + (ch & 1);
        z.h[s] = (f16)v;
      }
      uint4* dp = (uint4*)(xtb + i * 32);
      dp[0] = z.u4[0];
      dp[1] = z.u4[1];
    }
  }
  __syncthreads();   // drains DMA vmcnt + ds writes

  // ---- perception -> B1 ----
  f16x8 B1[4];
  perception(xtb, wv, pc, hi, B1);

  f32x16 acc[4];
  f16x8 B2[8], B3[8], B4[8];

  // ---- L1 (A in regs) ----
  bias_init(smem, 0, hi, acc);
#pragma unroll
  for (int kt = 0; kt < 4; ++kt)
#pragma unroll
    for (int mt = 0; mt < 4; ++mt)
      acc[mt] = __builtin_amdgcn_mfma_f32_32x32x16_f16(A1[kt * 4 + mt], B1[kt], acc[mt], 0, 0, 0);
  epilogue_swap(acc, B2);

  // ---- L2 (A from LDS) ----
  bias_init(smem, 128, hi, acc);
  gemm_lds<8>(smem, L2A_OFF, lane, B2, acc);
  epilogue_swap(acc, B3);

  // ---- L3 (A from LDS) ----
  bias_init(smem, 256, hi, acc);
  gemm_lds<8>(smem, L3A_OFF, lane, B3, acc);

  // ---- L4 A-frags from global (issued while L3 epilogue runs) ----
  f16x8 A4[8];
#pragma unroll
  for (int kt = 0; kt < 8; ++kt) A4[kt] = wp[5120 + kt * 64 + lane];
  epilogue_swap(acc, B4);

  // ---- L4 (M padded to 32) ----
  f32x16 a4;
#pragma unroll
  for (int r = 0; r < 16; ++r) a4[r] = 0.f;
#pragma unroll
  for (int kt = 0; kt < 8; ++kt)
    a4 = __builtin_amdgcn_mfma_f32_32x32x16_f16(A4[kt], B4[kt], a4, 0, 0, 0);

  // ---- update: x_new = x + dy * mask (exact f32 x re-read, L2-hot) ----
  {
    const int row = r0 + wv, col = c0 + pc;
    const float* xrb = xb + (row << 8) + col;
    float* xob = xn + (size_t)b * CHW + (row << 8) + col;
    const float mv = mask[(size_t)b * HW + (row << 8) + col];
#pragma unroll
    for (int r = 0; r < 8; ++r) {
      int ch = (r & 3) + 8 * (r >> 2) + 4 * hi;
      xob[(size_t)ch << 16] = xrb[(size_t)ch << 16] + a4[r] * mv;
    }
  }
}

// alive factor: row-block with LDS horizontal-max sharing; zero dead pixels
__global__ void alive_scale_k(const float* __restrict__ x, float* __restrict__ xn) {
  __shared__ float pm[4][258];
  const int col = threadIdx.x;
  const int row = blockIdx.x;
  const int b = blockIdx.y;
  const float NEG = -3.0e38f;
  float v0 = NEG, v1 = NEG, v2 = NEG, v3 = NEG;
  const size_t base0 = (size_t)b * CHW + ((size_t)row << 8) + col;
#pragma unroll
  for (int dr = -1; dr <= 1; ++dr) {
    int rr = row + dr;
    if ((unsigned)rr < NH) {
      long o = (long)base0 + dr * NW;
      v0 = fmaxf(v0, x[o]);
      v1 = fmaxf(v1, x[o + HW]);
      v2 = fmaxf(v2, xn[o]);
      v3 = fmaxf(v3, xn[o + HW]);
    }
  }
  pm[0][col + 1] = v0;
  pm[1][col + 1] = v1;
  pm[2][col + 1] = v2;
  pm[3][col + 1] = v3;
  if (col == 0) {
#pragma unroll
    for (int f = 0; f < 4; ++f) { pm[f][0] = NEG; pm[f][257] = NEG; }
  }
  __syncthreads();
  float p0 = fmaxf(fmaxf(pm[0][col], pm[0][col + 1]), pm[0][col + 2]);
  float p1 = fmaxf(fmaxf(pm[1][col], pm[1][col + 1]), pm[1][col + 2]);
  float p2 = fmaxf(fmaxf(pm[2][col], pm[2][col + 1]), pm[2][col + 2]);
  float p3 = fmaxf(fmaxf(pm[3][col], pm[3][col + 1]), pm[3][col + 2]);
  bool alive = ((fabsf(p0) + fabsf(p1)) > 0.01f) && ((fabsf(p2) + fabsf(p3)) > 0.01f);
  if (!alive) {
#pragma unroll
    for (int ch = 0; ch < NCH; ++ch) xn[base0 + ((size_t)ch << 16)] = 0.f;
  }
}

extern "C" void kernel_launch(void* const* d_in, const int* in_sizes, int n_in,
                              void* d_out, int out_size, void* d_ws, size_t ws_size,
                              hipStream_t stream) {
  const float* x    = (const float*)d_in[0];
  const float* w1   = (const float*)d_in[1];
  const float* b1   = (const float*)d_in[2];
  const float* w2   = (const float*)d_in[3];
  const float* b2   = (const float*)d_in[4];
  const float* w3   = (const float*)d_in[5];
  const float* b3   = (const float*)d_in[6];
  const float* w4   = (const float*)d_in[7];
  const float* mask = (const float*)d_in[8];

  float* wsf = (float*)d_ws;
  float* xn = (float*)d_out;

  hipFuncSetAttribute(reinterpret_cast<const void*>(nca_mlp_k),
                      hipFuncAttributeMaxDynamicSharedMemorySize, LDS_TOTAL);

  prep_k<<<178, 256, 0, stream>>>(w1, w2, w3, w4, b1, b2, b3, wsf);
  nca_mlp_k<<<dim3(NW / 32, NH / 8, NB), 512, LDS_TOTAL, stream>>>(x, wsf, mask, xn);
  alive_scale_k<<<dim3(NH, NB), 256, 0, stream>>>(x, xn);
}

// Round 11
// 240.750 us; speedup vs baseline: 1.7499x; 1.7499x over previous
//
#include <hip/hip_runtime.h>

typedef _Float16 f16;
typedef f16 f16x2 __attribute__((ext_vector_type(2)));
typedef f16 f16x8 __attribute__((ext_vector_type(8)));
typedef __fp16 h2v __attribute__((ext_vector_type(2)));
typedef float f32x4 __attribute__((ext_vector_type(4)));
typedef float f32x16 __attribute__((ext_vector_type(16)));
typedef unsigned int uint;

#define NCH 16
#define NB 32
#define NH 256
#define NW 256
#define HW 65536
#define CHW 1048576

// weight image (f16 A-frags + f32 bias frags): f16x8 idx WF1=0, WF2=1024, WF3=3072, WF4=5120
#define BIAS_BYTE 90112
#define WS_BYTES 91648
// x tile: f32 [ch16][rr10][cc66], staged by global_load_lds DMA
#define XT_OFF 91648
#define XT_FLOATS (16*10*66)
#define LDS_TOTAL (WS_BYTES + XT_FLOATS*4)   // 133888

__global__ void prep_k(const float* __restrict__ w1, const float* __restrict__ w2,
                       const float* __restrict__ w3, const float* __restrict__ w4,
                       const float* __restrict__ b1, const float* __restrict__ b2,
                       const float* __restrict__ b3, float* __restrict__ wsf) {
  f16* wf = (f16*)wsf;
  int id = blockIdx.x * 256 + threadIdx.x;
  if (id < 8192) {
    int j = id & 7, l = (id >> 3) & 63, mt = (id >> 9) & 3, kt = id >> 11;
    int o = mt * 32 + (l & 31), c = kt * 16 + (l >> 5) * 8 + j;
    wf[id] = (f16)w1[o * 64 + c];
  } else if (id < 24576) {
    int t = id - 8192;
    int j = t & 7, l = (t >> 3) & 63, mt = (t >> 9) & 3, kt = t >> 11;
    int o = mt * 32 + (l & 31), c = kt * 16 + (l >> 5) * 8 + j;
    wf[8192 + t] = (f16)w2[o * 128 + c];
  } else if (id < 40960) {
    int t = id - 24576;
    int j = t & 7, l = (t >> 3) & 63, mt = (t >> 9) & 3, kt = t >> 11;
    int o = mt * 32 + (l & 31), c = kt * 16 + (l >> 5) * 8 + j;
    wf[24576 + t] = (f16)w3[o * 128 + c];
  } else if (id < 45056) {
    int t = id - 40960;
    int j = t & 7, l = (t >> 3) & 63, kt = t >> 9;
    int m = l & 31, hh = l >> 5;
    int c = kt * 16 + hh * 8 + j;
    wf[40960 + t] = (m < 16) ? (f16)w4[m * 128 + c] : (f16)0.f;
  } else if (id < 45440) {
    int t = id - 45056;
    int r = t & 15, hh = (t >> 4) & 1, mt = (t >> 5) & 3, ly = t >> 7;
    const float* bb = (ly == 0) ? b1 : (ly == 1) ? b2 : b3;
    ((float*)((unsigned char*)wsf + BIAS_BYTE))[t] =
        bb[mt * 32 + (r & 3) + 8 * (r >> 2) + 4 * hh];
  }
}

__device__ __forceinline__ void pl32swap(uint& a, uint& b) {
  asm volatile("v_permlane32_swap_b32 %0, %1" : "+v"(a), "+v"(b));
}

__device__ __forceinline__ f16x8 mk8(uint a, uint b, uint c, uint d) {
  union { uint u[4]; f16x8 v; } z;
  z.u[0] = a; z.u[1] = b; z.u[2] = c; z.u[3] = d;
  return z.v;
}

__device__ __forceinline__ void gload_lds4(const float* g, float* l) {
  __builtin_amdgcn_global_load_lds(
      (const __attribute__((address_space(1))) unsigned int*)(const void*)g,
      (__attribute__((address_space(3))) unsigned int*)(void*)l, 4, 0, 0);
}

// Dual-half layer: acc init straight from LDS bias frags; each A-frag feeds 2 MFMAs
template <int NKT>
__device__ __forceinline__ void gemm2(const unsigned char* __restrict__ smem,
                                      int wfFragBase, int biasFloatOff, int lane, int hi,
                                      const f16x8* __restrict__ BL,
                                      const f16x8* __restrict__ BH,
                                      f32x16 accL[4], f32x16 accH[4]) {
#pragma unroll
  for (int mt = 0; mt < 4; ++mt) {
    const f32x16* bp =
        (const f32x16*)(smem + BIAS_BYTE + 4 * (biasFloatOff + (mt * 2 + hi) * 16));
    accL[mt] = *bp;
    accH[mt] = *bp;
  }
  const f16x8* A = (const f16x8*)smem + wfFragBase + lane;
  __builtin_amdgcn_s_setprio(1);
#pragma unroll
  for (int kt = 0; kt < NKT; ++kt) {
#pragma unroll
    for (int mt = 0; mt < 4; ++mt) {
      f16x8 a = A[(kt * 4 + mt) * 64];
      accL[mt] = __builtin_amdgcn_mfma_f32_32x32x16_f16(a, BL[kt], accL[mt], 0, 0, 0);
      accH[mt] = __builtin_amdgcn_mfma_f32_32x32x16_f16(a, BH[kt], accH[mt], 0, 0, 0);
    }
  }
  __builtin_amdgcn_s_setprio(0);
}

// lrelu in packed f16 (cvt_pkrtz + pk_mul + pk_max) -> permlane -> next B-frags
__device__ __forceinline__ void epilogue_swap(const f32x16 acc[4], f16x8 Bn[8]) {
  uint w[32];
  const h2v c001 = {(__fp16)0.01f, (__fp16)0.01f};
#pragma unroll
  for (int mt = 0; mt < 4; ++mt) {
#pragma unroll
    for (int i = 0; i < 8; ++i) {
      h2v u = __builtin_amdgcn_cvt_pkrtz(acc[mt][2 * i], acc[mt][2 * i + 1]);
      h2v s = u * c001;
      h2v m = __builtin_elementwise_max(u, s);
      w[mt * 8 + i] = __builtin_bit_cast(uint, m);
    }
  }
#pragma unroll
  for (int kt = 0; kt < 8; ++kt) {
    int mt = kt >> 1, sub = kt & 1;
    int W = mt * 8 + sub * 4;
    uint a0 = w[W], a1 = w[W + 1], a2 = w[W + 2], a3 = w[W + 3];
    pl32swap(a0, a2);
    pl32swap(a1, a3);
    Bn[kt] = mk8(a0, a1, a2, a3);
  }
}

// perception for one 32-px half from f32 tile: stencil math -> L1 B-frags
__device__ __forceinline__ void perception_f32(const float* __restrict__ xt,
                                               int wv, int pc, int hi, int h, f16x8 B1h[4]) {
  const int px = h * 32 + pc;
  uint yw[16];
#pragma unroll
  for (int kt = 0; kt < 4; ++kt) {
#pragma unroll
    for (int cp = 0; cp < 2; ++cp) {
      int c = kt * 4 + hi * 2 + cp;
      const float* xr = &xt[(c * 10 + wv) * 66 + px];
      float v00 = xr[0],   v01 = xr[1],   v02 = xr[2];
      float v10 = xr[66],  v11 = xr[67],  v12 = xr[68];
      float v20 = xr[132], v21 = xr[133], v22 = xr[134];
      float rs0 = v00 + v01 + v02, rs2 = v20 + v21 + v22;
      float fsx = (v02 - v00) + (v22 - v20) + 2.f * (v12 - v10);
      float fsy = (rs2 - rs0) + (v21 - v01);
      float flap = (rs0 + rs2 + v10 + v12) - 8.f * v11;
      h2v t0 = __builtin_amdgcn_cvt_pkrtz(v11, fsx);
      h2v t1 = __builtin_amdgcn_cvt_pkrtz(fsy, flap);
      yw[kt * 4 + cp * 2 + 0] = __builtin_bit_cast(uint, t0);
      yw[kt * 4 + cp * 2 + 1] = __builtin_bit_cast(uint, t1);
    }
  }
#pragma unroll
  for (int kt = 0; kt < 4; ++kt)
    B1h[kt] = mk8(yw[kt * 4], yw[kt * 4 + 1], yw[kt * 4 + 2], yw[kt * 4 + 3]);
}

// DMA one tile's interior: wave wv covers channels 2wv,2wv+1 (10 rows each); div-free
__device__ __forceinline__ void issue_tile_dma(const float* __restrict__ xb,
                                               float* __restrict__ xt,
                                               int cx, int ry, int wv, int lane) {
  const int gc0 = cx * 64;
#pragma unroll
  for (int half = 0; half < 2; ++half) {
    int ch = wv * 2 + half;
#pragma unroll
    for (int rr = 0; rr < 10; ++rr) {
      int gr = ry * 8 + rr - 1;
      float* ldst = xt + (ch * 10 + rr) * 66 + 1;
      if ((unsigned)gr < (unsigned)NH) {
        const float* g = xb + ((size_t)ch << 16) + (gr << 8) + gc0 + lane;
        gload_lds4(g, ldst);
      } else {
        ldst[lane] = 0.f;
      }
    }
  }
}

// edge-column fixup: load early (reg), store late
__device__ __forceinline__ float fixup_load(const float* __restrict__ xb,
                                            int cx, int ry, int tid) {
  if (tid >= 320) return 0.f;
  int row = tid >> 1, side = tid & 1;
  int ch = row / 10;
  int rr = row - ch * 10;
  int gr = ry * 8 + rr - 1;
  int gc = cx * 64 - 1 + side * 65;
  float v = 0.f;
  if ((unsigned)gr < (unsigned)NH && (unsigned)gc < (unsigned)NW)
    v = xb[((size_t)ch << 16) + (gr << 8) + gc];
  return v;
}

__device__ __forceinline__ void fixup_store(float* __restrict__ xt, int tid, float v) {
  if (tid < 320) {
    int row = tid >> 1, side = tid & 1;
    xt[row * 66 + side * 65] = v;
  }
}

__global__ __launch_bounds__(512, 1)
void nca_mlp_k(const float* __restrict__ x, const float* __restrict__ wsf,
               const float* __restrict__ mask, float* __restrict__ xn) {
  extern __shared__ unsigned char smem[];
  float* xt = (float*)(smem + XT_OFF);
  const int tid = threadIdx.x;
  const int lane = tid & 63;
  const int wv = tid >> 6;     // 0..7 = tile row
  const int pc = lane & 31;
  const int hi = lane >> 5;

  const int tile0 = blockIdx.x * 16;
  const int b = tile0 >> 7;                 // constant per block
  const float* xb = x + (size_t)b * CHW;
  float* xnb = xn + (size_t)b * CHW;
  const float* mb = mask + (size_t)b * HW;

  // ---- stage weights+bias once (linear b128 copy) ----
  {
    const uint4* src = (const uint4*)wsf;
    uint4* dst = (uint4*)smem;
    for (int i = tid; i < WS_BYTES / 16; i += 512) dst[i] = src[i];
  }
  // ---- prefetch first tile ----
  {
    int cx = tile0 & 3, ry = (tile0 >> 2) & 31;
    issue_tile_dma(xb, xt, cx, ry, wv, lane);
    float fv = fixup_load(xb, cx, ry, tid);
    fixup_store(xt, tid, fv);
  }
  __syncthreads();              // drains vmcnt (DMA) + lgkm (weights, fixup)

  for (int t = 0; t < 16; ++t) {
    const int tile = tile0 + t;
    const int cx = tile & 3, ry = (tile >> 2) & 31;

    // ---- perception (sole consumer of xt) ----
    f16x8 B1L[4], B1H[4];
    perception_f32(xt, wv, pc, hi, 0, B1L);
    perception_f32(xt, wv, pc, hi, 1, B1H);
    __syncthreads();            // everyone done reading xt

    // ---- issue next tile's DMA; drains at the iteration-end barrier ----
    float fv = 0.f;
    if (t < 15) {
      int cx2 = (tile + 1) & 3, ry2 = ((tile + 1) >> 2) & 31;
      issue_tile_dma(xb, xt, cx2, ry2, wv, lane);
      fv = fixup_load(xb, cx2, ry2, tid);
    }

    // ---- MLP chain ----
    f32x16 accL[4], accH[4];
    f16x8 B2L[8], B2H[8], B3L[8], B3H[8], B4L[8], B4H[8];

    gemm2<4>(smem, 0, 0, lane, hi, B1L, B1H, accL, accH);
    epilogue_swap(accL, B2L);
    epilogue_swap(accH, B2H);
    gemm2<8>(smem, 1024, 128, lane, hi, B2L, B2H, accL, accH);
    epilogue_swap(accL, B3L);
    epilogue_swap(accH, B3H);
    gemm2<8>(smem, 3072, 256, lane, hi, B3L, B3H, accL, accH);
    epilogue_swap(accL, B4L);
    epilogue_swap(accH, B4H);

    f32x16 a4L, a4H;
#pragma unroll
    for (int r = 0; r < 16; ++r) { a4L[r] = 0.f; a4H[r] = 0.f; }
    {
      const f16x8* A4 = (const f16x8*)smem + 5120 + lane;
      __builtin_amdgcn_s_setprio(1);
#pragma unroll
      for (int kt = 0; kt < 8; ++kt) {
        f16x8 a = A4[kt * 64];
        a4L = __builtin_amdgcn_mfma_f32_32x32x16_f16(a, B4L[kt], a4L, 0, 0, 0);
        a4H = __builtin_amdgcn_mfma_f32_32x32x16_f16(a, B4H[kt], a4H, 0, 0, 0);
      }
      __builtin_amdgcn_s_setprio(0);
    }

    // ---- update: x_new = x + dy * mask (exact f32 x re-read, L2-hot) ----
    {
      const int row = ry * 8 + wv;
      const float* xrb = xb + (row << 8);
      float* xob = xnb + (row << 8);
      const float* mrow = mb + (row << 8);
#pragma unroll
      for (int h = 0; h < 2; ++h) {
        int col = cx * 64 + h * 32 + pc;
        float mv = mrow[col];
#pragma unroll
        for (int r = 0; r < 8; ++r) {
          int ch = (r & 3) + 8 * (r >> 2) + 4 * hi;
          float dyv = h ? a4H[r] : a4L[r];
          xob[((size_t)ch << 16) + col] = xrb[((size_t)ch << 16) + col] + dyv * mv;
        }
      }
    }

    if (t < 15) fixup_store(xt, tid, fv);
    __syncthreads();            // drains DMA vmcnt + lgkm -> xt(t+1) ready
  }
}

// alive factor: row-block with LDS horizontal-max sharing; zero dead pixels
__global__ void alive_scale_k(const float* __restrict__ x, float* __restrict__ xn) {
  __shared__ float pm[4][258];
  const int col = threadIdx.x;
  const int row = blockIdx.x;
  const int b = blockIdx.y;
  const float NEG = -3.0e38f;
  float v0 = NEG, v1 = NEG, v2 = NEG, v3 = NEG;
  const size_t base0 = (size_t)b * CHW + ((size_t)row << 8) + col;
#pragma unroll
  for (int dr = -1; dr <= 1; ++dr) {
    int rr = row + dr;
    if ((unsigned)rr < NH) {
      long o = (long)base0 + dr * NW;
      v0 = fmaxf(v0, x[o]);
      v1 = fmaxf(v1, x[o + HW]);
      v2 = fmaxf(v2, xn[o]);
      v3 = fmaxf(v3, xn[o + HW]);
    }
  }
  pm[0][col + 1] = v0;
  pm[1][col + 1] = v1;
  pm[2][col + 1] = v2;
  pm[3][col + 1] = v3;
  if (col == 0) {
#pragma unroll
    for (int f = 0; f < 4; ++f) { pm[f][0] = NEG; pm[f][257] = NEG; }
  }
  __syncthreads();
  float p0 = fmaxf(fmaxf(pm[0][col], pm[0][col + 1]), pm[0][col + 2]);
  float p1 = fmaxf(fmaxf(pm[1][col], pm[1][col + 1]), pm[1][col + 2]);
  float p2 = fmaxf(fmaxf(pm[2][col], pm[2][col + 1]), pm[2][col + 2]);
  float p3 = fmaxf(fmaxf(pm[3][col], pm[3][col + 1]), pm[3][col + 2]);
  bool alive = ((fabsf(p0) + fabsf(p1)) > 0.01f) && ((fabsf(p2) + fabsf(p3)) > 0.01f);
  if (!alive) {
#pragma unroll
    for (int ch = 0; ch < NCH; ++ch) xn[base0 + ((size_t)ch << 16)] = 0.f;
  }
}

extern "C" void kernel_launch(void* const* d_in, const int* in_sizes, int n_in,
                              void* d_out, int out_size, void* d_ws, size_t ws_size,
                              hipStream_t stream) {
  const float* x    = (const float*)d_in[0];
  const float* w1   = (const float*)d_in[1];
  const float* b1   = (const float*)d_in[2];
  const float* w2   = (const float*)d_in[3];
  const float* b2   = (const float*)d_in[4];
  const float* w3   = (const float*)d_in[5];
  const float* b3   = (const float*)d_in[6];
  const float* w4   = (const float*)d_in[7];
  const float* mask = (const float*)d_in[8];

  float* wsf = (float*)d_ws;
  float* xn = (float*)d_out;

  hipFuncSetAttribute(reinterpret_cast<const void*>(nca_mlp_k),
                      hipFuncAttributeMaxDynamicSharedMemorySize, LDS_TOTAL);

  prep_k<<<178, 256, 0, stream>>>(w1, w2, w3, w4, b1, b2, b3, wsf);
  nca_mlp_k<<<256, 512, LDS_TOTAL, stream>>>(x, wsf, mask, xn);
  alive_scale_k<<<dim3(NH, NB), 256, 0, stream>>>(x, xn);
}